// Round 1
// baseline (1275.688 us; speedup 1.0000x reference)
//
#include <hip/hip_runtime.h>

// B=4, H=16, L=1024, D=1024, DH=64, P=1024
// q,k,v stored in ws as [B,H,L,DH] fp32

#define SCALE 0.125f  // 1/sqrt(64)

__device__ __forceinline__ int swz(int row, int u) {
    // tiles have 64-float rows = 16 float4 units; XOR-swizzle units to kill
    // the stride-64 bank conflict (G4 / T2)
    return (row << 4) | (u ^ ((row >> 2) & 15));
}

// ---------------- projection GEMM: out[b,h,l,d] = (X @ W + bias) split-heads ----------
// X: [4096,1024]  W: [1024,1024] (k,n)  out: [(b*16+h)*1024+l]*64+d
__global__ __launch_bounds__(256) void proj_kernel(
    const float* __restrict__ X, const float* __restrict__ W,
    const float* __restrict__ bias, float* __restrict__ out)
{
    __shared__ float4 As4[16 * 32];  // [k][m] transposed, 16x128 floats
    __shared__ float4 Bs4[16 * 32];  // [k][n], 16x128 floats
    const int tid = threadIdx.x;
    const int bm = blockIdx.y * 128;
    const int bn = blockIdx.x * 128;
    const int ty = tid >> 4, tx = tid & 15;
    const float4* X4 = (const float4*)X;
    const float4* W4 = (const float4*)W;
    float* AsF = (float*)As4;

    float acc[2][2][4][4];
#pragma unroll
    for (int a = 0; a < 2; ++a)
#pragma unroll
        for (int b = 0; b < 2; ++b)
#pragma unroll
            for (int i = 0; i < 4; ++i)
#pragma unroll
                for (int j = 0; j < 4; ++j) acc[a][b][i][j] = 0.f;

    for (int k0 = 0; k0 < 1024; k0 += 16) {
        __syncthreads();
        // stage A transposed: As[k][m] <- X[bm+m][k0+k]
#pragma unroll
        for (int it = 0; it < 2; ++it) {
            int idx = tid + it * 256;          // [0,512)
            int m = idx >> 2, kc = idx & 3;
            float4 x = X4[(size_t)(bm + m) * 256 + (k0 >> 2) + kc];
            AsF[(kc * 4 + 0) * 128 + m] = x.x;
            AsF[(kc * 4 + 1) * 128 + m] = x.y;
            AsF[(kc * 4 + 2) * 128 + m] = x.z;
            AsF[(kc * 4 + 3) * 128 + m] = x.w;
        }
        // stage B: Bs[k][n] <- W[k0+k][bn+n]
#pragma unroll
        for (int it = 0; it < 2; ++it) {
            int idx = tid + it * 256;          // [0,512)
            int k = idx >> 5, un = idx & 31;
            Bs4[k * 32 + un] = W4[(size_t)(k0 + k) * 256 + (bn >> 2) + un];
        }
        __syncthreads();
#pragma unroll
        for (int kk = 0; kk < 16; ++kk) {
            float4 a0 = As4[kk * 32 + ty];
            float4 a1 = As4[kk * 32 + 16 + ty];
            float4 b0 = Bs4[kk * 32 + tx];
            float4 b1 = Bs4[kk * 32 + 16 + tx];
            float av[2][4] = {{a0.x, a0.y, a0.z, a0.w}, {a1.x, a1.y, a1.z, a1.w}};
            float bw[2][4] = {{b0.x, b0.y, b0.z, b0.w}, {b1.x, b1.y, b1.z, b1.w}};
#pragma unroll
            for (int rh = 0; rh < 2; ++rh)
#pragma unroll
                for (int ch = 0; ch < 2; ++ch)
#pragma unroll
                    for (int i = 0; i < 4; ++i)
#pragma unroll
                        for (int j = 0; j < 4; ++j)
                            acc[rh][ch][i][j] += av[rh][i] * bw[ch][j];
        }
    }
    const float4* bias4 = (const float4*)bias;
#pragma unroll
    for (int rh = 0; rh < 2; ++rh)
#pragma unroll
        for (int ch = 0; ch < 2; ++ch) {
            float4 bv4 = bias4[(bn >> 2) + ch * 16 + tx];
#pragma unroll
            for (int i = 0; i < 4; ++i) {
                int m = bm + rh * 64 + ty * 4 + i;
                int n = bn + ch * 64 + tx * 4;
                int b = m >> 10, l = m & 1023;
                int h = n >> 6, d = n & 63;
                float4 o;
                o.x = acc[rh][ch][i][0] + bv4.x;
                o.y = acc[rh][ch][i][1] + bv4.y;
                o.z = acc[rh][ch][i][2] + bv4.z;
                o.w = acc[rh][ch][i][3] + bv4.w;
                *(float4*)&out[(((size_t)b * 16 + h) * 1024 + l) * 64 + d] = o;
            }
        }
}

// ---------------- fused attention with relative_key_query bias ----------------
// one block = (b, h, 64 q-rows); iterate 16 k-tiles of 64; online softmax
__global__ __launch_bounds__(256) void attn_kernel(
    const float* __restrict__ Q, const float* __restrict__ K,
    const float* __restrict__ V, const float* __restrict__ mask,
    const float* __restrict__ de, float* __restrict__ out)
{
    __shared__ float4 Qs[64 * 16];
    __shared__ float4 Ks[64 * 16];
    __shared__ float4 Vs[64 * 16];
    __shared__ float4 Ss[64 * 16];
    __shared__ float4 Des[127 * 16];   // dist_emb window rows [tbase, tbase+126]
    __shared__ float m_s[64], l_s[64], alpha_s[64];

    const int tid = threadIdx.x;
    const int ty = tid >> 4, tx = tid & 15;   // 16x16 thread grid, 4x4 micro-tile
    const int l0 = blockIdx.x * 64;
    const int h = blockIdx.y, b = blockIdx.z;
    const size_t bh = ((size_t)b * 16 + h) * 1024;

    const float4* Q4 = (const float4*)Q;
    const float4* K4 = (const float4*)K;
    const float4* V4 = (const float4*)V;
    const float4* DE4 = (const float4*)de;
    const float4* MSK4 = (const float4*)mask;

    // stage Q once
    for (int idx = tid; idx < 64 * 16; idx += 256) {
        int r = idx >> 4, u = idx & 15;
        Qs[swz(r, u)] = Q4[(bh + l0 + r) * 16 + u];
    }
    if (tid < 64) { m_s[tid] = -1e30f; l_s[tid] = 0.f; }

    float o[4][4] = {};

    for (int r0 = 0; r0 < 1024; r0 += 64) {
        __syncthreads();   // prior-iter PV reads done before restaging
        // stage K, V tiles
        for (int idx = tid; idx < 64 * 16; idx += 256) {
            int r = idx >> 4, u = idx & 15;
            Ks[swz(r, u)] = K4[(bh + r0 + r) * 16 + u];
            Vs[swz(r, u)] = V4[(bh + r0 + r) * 16 + u];
        }
        // stage dist_emb window: t = (i - j) + l0 - r0 + 1023, i,j in [0,64)
        const int tbase = l0 - r0 + 960;   // always in [0, 1920]
        for (int idx = tid; idx < 127 * 16; idx += 256) {
            int r = idx >> 4, u = idx & 15;
            Des[swz(r, u)] = DE4[(size_t)(tbase + r) * 16 + u];
        }
        __syncthreads();

        // ---- S tile: s = q.k + (q+k).de[l-r+1023]
        float s[4][4] = {};
        const int dbase = 4 * (ty - tx) + 60;  // de row for (ii-jj) = -3
        for (int d4 = 0; d4 < 16; ++d4) {
            float4 qv[4], kv[4], dv[7];
#pragma unroll
            for (int ii = 0; ii < 4; ++ii) qv[ii] = Qs[swz(ty * 4 + ii, d4)];
#pragma unroll
            for (int jj = 0; jj < 4; ++jj) kv[jj] = Ks[swz(tx * 4 + jj, d4)];
#pragma unroll
            for (int k = 0; k < 7; ++k) dv[k] = Des[swz(dbase + k, d4)];
#pragma unroll
            for (int ii = 0; ii < 4; ++ii)
#pragma unroll
                for (int jj = 0; jj < 4; ++jj) {
                    const float4 q = qv[ii], kk = kv[jj], dd = dv[ii - jj + 3];
                    s[ii][jj] += q.x * kk.x + (q.x + kk.x) * dd.x;
                    s[ii][jj] += q.y * kk.y + (q.y + kk.y) * dd.y;
                    s[ii][jj] += q.z * kk.z + (q.z + kk.z) * dd.z;
                    s[ii][jj] += q.w * kk.w + (q.w + kk.w) * dd.w;
                }
        }
        // scale + mask, write to Ss
        float4 mv = MSK4[(b * 1024 + r0) / 4 + tx];
#pragma unroll
        for (int ii = 0; ii < 4; ++ii) {
            float4 sv;
            sv.x = s[ii][0] * SCALE + mv.x;
            sv.y = s[ii][1] * SCALE + mv.y;
            sv.z = s[ii][2] * SCALE + mv.z;
            sv.w = s[ii][3] * SCALE + mv.w;
            Ss[swz(ty * 4 + ii, tx)] = sv;
        }
        __syncthreads();

        // ---- online softmax: 4 threads per row
        {
            const int row = tid >> 2, t4 = tid & 3;
            float4 pv[4];
            float mx = -1e30f;
#pragma unroll
            for (int uu = 0; uu < 4; ++uu) {
                pv[uu] = Ss[swz(row, t4 * 4 + uu)];
                mx = fmaxf(mx, fmaxf(fmaxf(pv[uu].x, pv[uu].y), fmaxf(pv[uu].z, pv[uu].w)));
            }
            mx = fmaxf(mx, __shfl_xor(mx, 1));
            mx = fmaxf(mx, __shfl_xor(mx, 2));
            float m_old = m_s[row];             // all 4 lanes read (same wave, lockstep)
            float m_new = fmaxf(m_old, mx);
            float alpha = __expf(m_old - m_new);
            float ssum = 0.f;
#pragma unroll
            for (int uu = 0; uu < 4; ++uu) {
                pv[uu].x = __expf(pv[uu].x - m_new);
                pv[uu].y = __expf(pv[uu].y - m_new);
                pv[uu].z = __expf(pv[uu].z - m_new);
                pv[uu].w = __expf(pv[uu].w - m_new);
                ssum += pv[uu].x + pv[uu].y + pv[uu].z + pv[uu].w;
                Ss[swz(row, t4 * 4 + uu)] = pv[uu];
            }
            ssum += __shfl_xor(ssum, 1);
            ssum += __shfl_xor(ssum, 2);
            if (t4 == 0) {
                m_s[row] = m_new;
                l_s[row] = l_s[row] * alpha + ssum;
                alpha_s[row] = alpha;
            }
        }
        __syncthreads();

        // ---- PV accumulate
#pragma unroll
        for (int ii = 0; ii < 4; ++ii) {
            float al = alpha_s[ty * 4 + ii];
#pragma unroll
            for (int jj = 0; jj < 4; ++jj) o[ii][jj] *= al;
        }
        for (int r4 = 0; r4 < 16; ++r4) {
            float4 p4[4], v4[4];
#pragma unroll
            for (int ii = 0; ii < 4; ++ii) p4[ii] = Ss[swz(ty * 4 + ii, r4)];
#pragma unroll
            for (int c = 0; c < 4; ++c) v4[c] = Vs[swz(r4 * 4 + c, tx)];
#pragma unroll
            for (int ii = 0; ii < 4; ++ii) {
                o[ii][0] += p4[ii].x * v4[0].x + p4[ii].y * v4[1].x + p4[ii].z * v4[2].x + p4[ii].w * v4[3].x;
                o[ii][1] += p4[ii].x * v4[0].y + p4[ii].y * v4[1].y + p4[ii].z * v4[2].y + p4[ii].w * v4[3].y;
                o[ii][2] += p4[ii].x * v4[0].z + p4[ii].y * v4[1].z + p4[ii].z * v4[2].z + p4[ii].w * v4[3].z;
                o[ii][3] += p4[ii].x * v4[0].w + p4[ii].y * v4[1].w + p4[ii].z * v4[2].w + p4[ii].w * v4[3].w;
            }
        }
    }

    // epilogue: out[b, l, h*64+d]
#pragma unroll
    for (int ii = 0; ii < 4; ++ii) {
        float inv = 1.0f / l_s[ty * 4 + ii];
        float4 ov;
        ov.x = o[ii][0] * inv;
        ov.y = o[ii][1] * inv;
        ov.z = o[ii][2] * inv;
        ov.w = o[ii][3] * inv;
        *(float4*)&out[((size_t)(b * 1024 + l0 + ty * 4 + ii)) * 1024 + h * 64 + tx * 4] = ov;
    }
}

extern "C" void kernel_launch(void* const* d_in, const int* in_sizes, int n_in,
                              void* d_out, int out_size, void* d_ws, size_t ws_size,
                              hipStream_t stream) {
    const float* hs   = (const float*)d_in[0];
    const float* mask = (const float*)d_in[1];
    const float* Wq   = (const float*)d_in[2];
    const float* bq   = (const float*)d_in[3];
    const float* Wk   = (const float*)d_in[4];
    const float* bk   = (const float*)d_in[5];
    const float* Wv   = (const float*)d_in[6];
    const float* bv   = (const float*)d_in[7];
    const float* de   = (const float*)d_in[8];
    float* out = (float*)d_out;

    const size_t per = (size_t)4 * 16 * 1024 * 64;  // 4.19M floats each
    float* Qb = (float*)d_ws;
    float* Kb = Qb + per;
    float* Vb = Kb + per;

    dim3 pgrid(8, 32);   // N/128, M/128
    proj_kernel<<<pgrid, 256, 0, stream>>>(hs, Wq, bq, Qb);
    proj_kernel<<<pgrid, 256, 0, stream>>>(hs, Wk, bk, Kb);
    proj_kernel<<<pgrid, 256, 0, stream>>>(hs, Wv, bv, Vb);

    dim3 agrid(16, 16, 4);  // l-tiles, heads, batch
    attn_kernel<<<agrid, 256, 0, stream>>>(Qb, Kb, Vb, mask, de, out);
}